// Round 2
// baseline (291.854 us; speedup 1.0000x reference)
//
#include <hip/hip_runtime.h>
#include <hip/hip_bf16.h>

#define Nn 302
#define Tt 2048
#define TEx 2080
#define Kk 33
#define ODOR 16
#define DTc 0.2f
#define NT (Nn*Tt)

__device__ __forceinline__ float bu2f(unsigned short u){ return __uint_as_float(((unsigned int)u) << 16); }
__device__ __forceinline__ unsigned short f2bu(float x){ __hip_bfloat16 h = __float2bfloat16(x); unsigned short u; __builtin_memcpy(&u, &h, 2); return u; }
__device__ __forceinline__ unsigned int pk2(float a, float b){ return (unsigned int)f2bu(a) | ((unsigned int)f2bu(b) << 16); }
__device__ __forceinline__ float lo2f(unsigned int u){ return __uint_as_float(u << 16); }
__device__ __forceinline__ float hi2f(unsigned int u){ return __uint_as_float(u & 0xffff0000u); }

// dtype probe: bf16 data reinterpreted as f32 words has exponent-field >= 0xC0
// for any bf16 magnitude in [0.008, 2); f32 N(0,1) data never does.
__device__ __forceinline__ bool detect_bf16(const void* epsv){
    const unsigned int* u = (const unsigned int*)epsv;
    int cnt = 0;
    #pragma unroll
    for (int i = 0; i < 8; i++){
        unsigned int ex = (u[i] >> 23) & 0xFFu;
        cnt += (ex >= 0xC0u) ? 1 : 0;
    }
    return cnt > 0;
}

template<bool B> struct IO {
    static __device__ __forceinline__ float ld(const void* p, size_t i){
        if constexpr (B) return bu2f(((const unsigned short*)p)[i]);
        else             return ((const float*)p)[i];
    }
    static __device__ __forceinline__ void ld8(const void* p, size_t i, float* v){
        if constexpr (B){
            uint4 u = *(const uint4*)((const unsigned short*)p + i);
            v[0]=lo2f(u.x); v[1]=hi2f(u.x); v[2]=lo2f(u.y); v[3]=hi2f(u.y);
            v[4]=lo2f(u.z); v[5]=hi2f(u.z); v[6]=lo2f(u.w); v[7]=hi2f(u.w);
        } else {
            float4 a = *(const float4*)((const float*)p + i);
            float4 b = *(const float4*)((const float*)p + i + 4);
            v[0]=a.x; v[1]=a.y; v[2]=a.z; v[3]=a.w;
            v[4]=b.x; v[5]=b.y; v[6]=b.z; v[7]=b.w;
        }
    }
    static __device__ __forceinline__ void st8(void* p, size_t i, const float* v){
        if constexpr (B){
            *(uint4*)((unsigned short*)p + i) =
                make_uint4(pk2(v[0],v[1]), pk2(v[2],v[3]), pk2(v[4],v[5]), pk2(v[6],v[7]));
        } else {
            *(float4*)((float*)p + i)     = make_float4(v[0],v[1],v[2],v[3]);
            *(float4*)((float*)p + i + 4) = make_float4(v[4],v[5],v[6],v[7]);
        }
    }
    static __device__ __forceinline__ void st(void* p, size_t i, float x){
        if constexpr (B) ((unsigned short*)p)[i] = f2bu(x);
        else             ((float*)p)[i] = x;
    }
    // two consecutive elements starting at element 2*pairIdx
    static __device__ __forceinline__ float2 ld2(const void* p, size_t pairIdx){
        if constexpr (B){
            unsigned int u = ((const unsigned int*)p)[pairIdx];
            return make_float2(lo2f(u), hi2f(u));
        } else {
            return ((const float2*)p)[pairIdx];
        }
    }
};

// output regions (element offsets, x NT):
// 0 mu_neuron_voltage, 1 mu_fluorescence, 2 mu_v, 3 logvar_v, 4 sample_v,
// 5 calcium_activation, 6 mu_calcium, 7 recurrent_in, 8 sensory_input
template<bool B>
__device__ __forceinline__ void* region(void* outv, int r){
    const size_t es = B ? 2 : 4;
    return (void*)((char*)outv + (size_t)r * NT * es);
}

// ---------------- Kernel A: encode + depthwise conv + pointwise ----------------
template<bool B>
__device__ void bodyA(const void* fr, const void* odor, const void* eps,
                      const void* Wenc, const void* benc, const void* mask,
                      const void* Wmf, const void* Wms, const void* bmu,
                      const void* Wlf, const void* Wls, const void* blv,
                      const void* waff, const void* baff, void* outv,
                      float* frs, float* ses, float* wv)
{
    const int n = blockIdx.x;
    const int tid = threadIdx.x;
    float* wmf_s = wv;        float* wms_s = wv + Kk;
    float* wlf_s = wv + 2*Kk; float* wls_s = wv + 3*Kk;
    float* wenc_s = wv + 4*Kk;

    if (tid < Kk){
        wmf_s[tid] = IO<B>::ld(Wmf, n*Kk + tid);
        wms_s[tid] = IO<B>::ld(Wms, n*Kk + tid);
        wlf_s[tid] = IO<B>::ld(Wlf, n*Kk + tid);
        wls_s[tid] = IO<B>::ld(Wls, n*Kk + tid);
    }
    if (tid < ODOR) wenc_s[tid] = IO<B>::ld(Wenc, n*ODOR + tid);

    for (int c = tid; c < TEx/8; c += 256){
        float v[8];
        IO<B>::ld8(fr, (size_t)n*TEx + c*8, v);
        #pragma unroll
        for (int j = 0; j < 8; j++) frs[c*8 + j] = v[j];
    }
    __syncthreads();

    const float benc_f = IO<B>::ld(benc, n);
    const float mask_f = IO<B>::ld(mask, n);
    for (int t = tid; t < TEx; t += 256){
        float acc = benc_f;
        #pragma unroll
        for (int o = 0; o < ODOR; o++) acc += wenc_s[o] * IO<B>::ld(odor, (size_t)o*TEx + t);
        ses[t] = mask_f * acc;
    }
    __syncthreads();

    const float bmu_f  = IO<B>::ld(bmu, n);
    const float blv_f  = IO<B>::ld(blv, n);
    const float waff_f = IO<B>::ld(waff, n);
    const float baff_f = IO<B>::ld(baff, n);

    const int t0 = tid*8;
    float xf[40], xs[40];
    #pragma unroll
    for (int i = 0; i < 10; i++){
        float4 a = *(const float4*)&frs[t0 + 4*i];
        xf[4*i]=a.x; xf[4*i+1]=a.y; xf[4*i+2]=a.z; xf[4*i+3]=a.w;
        float4 b = *(const float4*)&ses[t0 + 4*i];
        xs[4*i]=b.x; xs[4*i+1]=b.y; xs[4*i+2]=b.z; xs[4*i+3]=b.w;
    }

    float aMu[8], aLv[8];
    #pragma unroll
    for (int j = 0; j < 8; j++){ aMu[j]=bmu_f; aLv[j]=blv_f; }
    #pragma unroll
    for (int k = 0; k < Kk; k++){
        float wf = wmf_s[k], wsn = wms_s[k], vf = wlf_s[k], vsn = wls_s[k];
        #pragma unroll
        for (int j = 0; j < 8; j++){
            aMu[j] = fmaf(xf[j+k], wf, fmaf(xs[j+k], wsn, aMu[j]));
            aLv[j] = fmaf(xf[j+k], vf, fmaf(xs[j+k], vsn, aLv[j]));
        }
    }

    const size_t base = (size_t)n*Tt + t0;
    float ev[8];
    IO<B>::ld8(eps, base, ev);

    float smp[8], cav[8], siv[8];
    #pragma unroll
    for (int j = 0; j < 8; j++){
        float s = aMu[j] + expf(0.5f*aLv[j])*ev[j];
        smp[j] = s;
        float x = waff_f*s + baff_f;
        cav[j] = (x > 20.f) ? x : log1pf(expf(x));
        siv[j] = ses[t0 + j + 16];   // crop = 16
    }

    IO<B>::st8(region<B>(outv,2), base, aMu);
    IO<B>::st8(region<B>(outv,3), base, aLv);
    IO<B>::st8(region<B>(outv,4), base, smp);
    IO<B>::st8(region<B>(outv,5), base, cav);
    IO<B>::st8(region<B>(outv,8), base, siv);
}

__global__ __launch_bounds__(256) void kA(
    const void* fr, const void* odor, const void* eps,
    const void* Wenc, const void* benc, const void* mask,
    const void* Wmf, const void* Wms, const void* bmu,
    const void* Wlf, const void* Wls, const void* blv,
    const void* waff, const void* baff, void* outv)
{
    __shared__ float frs[TEx];
    __shared__ float ses[TEx];
    __shared__ float wv[4*Kk + ODOR];
    if (detect_bf16(eps))
        bodyA<true >(fr,odor,eps,Wenc,benc,mask,Wmf,Wms,bmu,Wlf,Wls,blv,waff,baff,outv,frs,ses,wv);
    else
        bodyA<false>(fr,odor,eps,Wenc,benc,mask,Wmf,Wms,bmu,Wlf,Wls,blv,waff,baff,outv,frs,ses,wv);
}

// ---------------- Kernel B: recurrent_in + voltage update ----------------
// block (64,4): 64 t-cols x 32 n-rows (8 rows/thread). grid (T/64, ceil(N/32))
template<bool B>
__device__ void bodyB(const void* Wch, const void* Wel,
                      const void* bias, const void* tau, void* outv)
{
    const int tx = threadIdx.x;
    const int ty = threadIdx.y;
    const int t  = blockIdx.x*64 + tx;
    const int n0 = blockIdx.y*32;

    const void* o_sv = region<B>(outv, 4);
    const void* o_si = region<B>(outv, 8);
    void* o_mnv = region<B>(outv, 0);
    void* o_rec = region<B>(outv, 7);

    int nn[8]; size_t pb[8]; float acc[8];
    #pragma unroll
    for (int r = 0; r < 8; r++){
        int v = n0 + ty + 4*r;
        nn[r] = v;
        int c = (v < Nn) ? v : 0;
        pb[r] = (size_t)c * 151;       // pair index of row start (302 elems = 151 pairs)
        acc[r] = 0.f;
    }

    for (int mh = 0; mh < 151; mh++){
        const int m = mh*2;
        float s0 = IO<B>::ld(o_sv, (size_t)m*Tt + t);
        float s1 = IO<B>::ld(o_sv, (size_t)(m+1)*Tt + t);
        float a0 = fmaxf(s0, 0.f), a1 = fmaxf(s1, 0.f);
        #pragma unroll
        for (int r = 0; r < 8; r++){
            float2 wc = IO<B>::ld2(Wch, pb[r] + mh);
            float2 we = IO<B>::ld2(Wel, pb[r] + mh);
            acc[r] = fmaf(wc.x, a0, acc[r]);
            acc[r] = fmaf(wc.y, a1, acc[r]);
            acc[r] = fmaf(we.x, s0, acc[r]);
            acc[r] = fmaf(we.y, s1, acc[r]);
        }
    }

    #pragma unroll
    for (int r = 0; r < 8; r++){
        if (nn[r] < Nn){
            const size_t idx = (size_t)nn[r]*Tt + t;
            float si  = IO<B>::ld(o_si, idx);
            float rec = acc[r] + si;
            IO<B>::st(o_rec, idx, rec);
            float sv = IO<B>::ld(o_sv, idx);
            float ta = IO<B>::ld(tau, nn[r]);
            float bi = IO<B>::ld(bias, nn[r]);
            IO<B>::st(o_mnv, idx, sv + (DTc/ta)*(-sv + rec + bi));
        }
    }
}

__global__ __launch_bounds__(256) void kB(
    const void* Wch, const void* Wel, const void* bias, const void* tau,
    const void* eps, void* outv)
{
    if (detect_bf16(eps)) bodyB<true >(Wch, Wel, bias, tau, outv);
    else                  bodyB<false>(Wch, Wel, bias, tau, outv);
}

// ---------------- Kernel C: calcium IIR scan ----------------
template<bool B>
__device__ void bodyC(const void* fft, const void* scale, const void* shift,
                      const void* ctau, void* outv, float* Bs, float* Ps)
{
    const int n = blockIdx.x;
    const int tid = threadIdx.x;
    const void* o_ca = region<B>(outv, 5);
    void* o_fl = region<B>(outv, 1);
    void* o_mc = region<B>(outv, 6);

    const float sc = IO<B>::ld(scale, n);
    const float sh = IO<B>::ld(shift, n);
    const float ct = IO<B>::ld(ctau, n);
    const float decay = expf(-DTc/ct);

    const int t0 = tid*8;
    const size_t base = (size_t)n*Tt + t0;
    float x[8];
    IO<B>::ld8(o_ca, base, x);

    float b = 0.f;
    #pragma unroll
    for (int j = 0; j < 8; j++) b = fmaf(decay, b, x[j]);
    Bs[tid] = b;
    __syncthreads();

    if (tid == 0){
        const float init = (IO<B>::ld(fft, (size_t)n*Tt) - sh)/sc;
        const float d2 = decay*decay, d4 = d2*d2, d8 = d4*d4;
        float P = init;
        for (int i = 0; i < 256; i++){ Ps[i] = P; P = fmaf(d8, P, Bs[i]); }
    }
    __syncthreads();

    float c = Ps[tid];
    float mc[8], fl[8];
    #pragma unroll
    for (int j = 0; j < 8; j++){
        c = fmaf(decay, c, x[j]);
        mc[j] = c;
        fl[j] = fmaf(sc, c, sh);
    }
    IO<B>::st8(o_mc, base, mc);
    IO<B>::st8(o_fl, base, fl);
}

__global__ __launch_bounds__(256) void kC(
    const void* fft, const void* scale, const void* shift, const void* ctau,
    const void* eps, void* outv)
{
    __shared__ float Bs[256];
    __shared__ float Ps[256];
    if (detect_bf16(eps)) bodyC<true >(fft, scale, shift, ctau, outv, Bs, Ps);
    else                  bodyC<false>(fft, scale, shift, ctau, outv, Bs, Ps);
}

extern "C" void kernel_launch(void* const* d_in, const int* in_sizes, int n_in,
                              void* d_out, int out_size, void* d_ws, size_t ws_size,
                              hipStream_t stream) {
    const void* fr   = d_in[0];
    const void* fft  = d_in[1];
    const void* odor = d_in[2];
    const void* eps  = d_in[3];
    const void* Wenc = d_in[4];
    const void* benc = d_in[5];
    const void* mask = d_in[6];
    const void* Wmf  = d_in[7];
    const void* Wms  = d_in[8];
    const void* bmu  = d_in[9];
    const void* Wlf  = d_in[10];
    const void* Wls  = d_in[11];
    const void* blv  = d_in[12];
    const void* Wch  = d_in[13];
    const void* Wel  = d_in[14];
    const void* bias = d_in[15];
    const void* tau  = d_in[16];
    const void* waff = d_in[17];
    const void* baff = d_in[18];
    const void* scal = d_in[19];
    const void* shft = d_in[20];
    const void* ctau = d_in[21];

    kA<<<Nn, 256, 0, stream>>>(fr, odor, eps, Wenc, benc, mask, Wmf, Wms, bmu,
                               Wlf, Wls, blv, waff, baff, d_out);

    kB<<<dim3(Tt/64, (Nn+31)/32), dim3(64,4), 0, stream>>>(
        Wch, Wel, bias, tau, eps, d_out);

    kC<<<Nn, 256, 0, stream>>>(fft, scal, shft, ctau, eps, d_out);
}

// Round 3
// 290.421 us; speedup vs baseline: 1.0049x; 1.0049x over previous
//
#include <hip/hip_runtime.h>
#include <hip/hip_bf16.h>

#define Nn 302
#define Tt 2048
#define TEx 2080
#define Kk 33
#define ODOR 16
#define DTc 0.2f
#define NT (Nn*Tt)
#define KX 640          // padded K for GEMM: act cols [0,320), sv cols [320,640)
#define MW 304          // padded M rows of W_cat

typedef __attribute__((ext_vector_type(8))) short short8;
typedef __attribute__((ext_vector_type(4))) float f32x4;

__device__ __forceinline__ float bu2f(unsigned short u){ return __uint_as_float(((unsigned int)u) << 16); }
__device__ __forceinline__ unsigned short f2bu(float x){ __hip_bfloat16 h = __float2bfloat16(x); unsigned short u; __builtin_memcpy(&u, &h, 2); return u; }
__device__ __forceinline__ unsigned int pk2(float a, float b){ return (unsigned int)f2bu(a) | ((unsigned int)f2bu(b) << 16); }
__device__ __forceinline__ float lo2f(unsigned int u){ return __uint_as_float(u << 16); }
__device__ __forceinline__ float hi2f(unsigned int u){ return __uint_as_float(u & 0xffff0000u); }

__device__ __forceinline__ bool detect_bf16(const void* epsv){
    const unsigned int* u = (const unsigned int*)epsv;
    int cnt = 0;
    #pragma unroll
    for (int i = 0; i < 8; i++){
        unsigned int ex = (u[i] >> 23) & 0xFFu;
        cnt += (ex >= 0xC0u) ? 1 : 0;
    }
    return cnt > 0;
}

template<bool B> struct IO {
    static __device__ __forceinline__ float ld(const void* p, size_t i){
        if constexpr (B) return bu2f(((const unsigned short*)p)[i]);
        else             return ((const float*)p)[i];
    }
    static __device__ __forceinline__ void ld8(const void* p, size_t i, float* v){
        if constexpr (B){
            uint4 u = *(const uint4*)((const unsigned short*)p + i);
            v[0]=lo2f(u.x); v[1]=hi2f(u.x); v[2]=lo2f(u.y); v[3]=hi2f(u.y);
            v[4]=lo2f(u.z); v[5]=hi2f(u.z); v[6]=lo2f(u.w); v[7]=hi2f(u.w);
        } else {
            float4 a = *(const float4*)((const float*)p + i);
            float4 b = *(const float4*)((const float*)p + i + 4);
            v[0]=a.x; v[1]=a.y; v[2]=a.z; v[3]=a.w;
            v[4]=b.x; v[5]=b.y; v[6]=b.z; v[7]=b.w;
        }
    }
    static __device__ __forceinline__ void st8(void* p, size_t i, const float* v){
        if constexpr (B){
            *(uint4*)((unsigned short*)p + i) =
                make_uint4(pk2(v[0],v[1]), pk2(v[2],v[3]), pk2(v[4],v[5]), pk2(v[6],v[7]));
        } else {
            *(float4*)((float*)p + i)     = make_float4(v[0],v[1],v[2],v[3]);
            *(float4*)((float*)p + i + 4) = make_float4(v[4],v[5],v[6],v[7]);
        }
    }
    static __device__ __forceinline__ void st(void* p, size_t i, float x){
        if constexpr (B) ((unsigned short*)p)[i] = f2bu(x);
        else             ((float*)p)[i] = x;
    }
    static __device__ __forceinline__ float2 ld2(const void* p, size_t pairIdx){
        if constexpr (B){
            unsigned int u = ((const unsigned int*)p)[pairIdx];
            return make_float2(lo2f(u), hi2f(u));
        } else {
            return ((const float2*)p)[pairIdx];
        }
    }
};

// output regions (x NT): 0 mnv, 1 fluor, 2 mu_v, 3 logvar, 4 sample_v,
// 5 calcium_act, 6 mu_calcium, 7 recurrent_in, 8 sensory_input
template<bool B>
__device__ __forceinline__ void* region(void* outv, int r){
    const size_t es = B ? 2 : 4;
    return (void*)((char*)outv + (size_t)r * NT * es);
}

// ---------------- Kernel A ----------------
template<bool B>
__device__ void bodyA(const void* fr, const void* odor, const void* eps,
                      const void* Wenc, const void* benc, const void* mask,
                      const void* Wmf, const void* Wms, const void* bmu,
                      const void* Wlf, const void* Wls, const void* blv,
                      const void* waff, const void* baff, void* outv,
                      float* frs, float* ses, float* wv)
{
    const int n = blockIdx.x;
    const int tid = threadIdx.x;
    float* wmf_s = wv;        float* wms_s = wv + Kk;
    float* wlf_s = wv + 2*Kk; float* wls_s = wv + 3*Kk;
    float* wenc_s = wv + 4*Kk;

    if (tid < Kk){
        wmf_s[tid] = IO<B>::ld(Wmf, n*Kk + tid);
        wms_s[tid] = IO<B>::ld(Wms, n*Kk + tid);
        wlf_s[tid] = IO<B>::ld(Wlf, n*Kk + tid);
        wls_s[tid] = IO<B>::ld(Wls, n*Kk + tid);
    }
    if (tid < ODOR) wenc_s[tid] = IO<B>::ld(Wenc, n*ODOR + tid);

    for (int c = tid; c < TEx/8; c += 256){
        float v[8];
        IO<B>::ld8(fr, (size_t)n*TEx + c*8, v);
        #pragma unroll
        for (int j = 0; j < 8; j++) frs[c*8 + j] = v[j];
    }
    __syncthreads();

    const float benc_f = IO<B>::ld(benc, n);
    const float mask_f = IO<B>::ld(mask, n);
    for (int c = tid; c < TEx/8; c += 256){
        float acc[8];
        #pragma unroll
        for (int j = 0; j < 8; j++) acc[j] = benc_f;
        #pragma unroll
        for (int o = 0; o < ODOR; o++){
            float v[8];
            IO<B>::ld8(odor, (size_t)o*TEx + c*8, v);
            #pragma unroll
            for (int j = 0; j < 8; j++) acc[j] = fmaf(wenc_s[o], v[j], acc[j]);
        }
        #pragma unroll
        for (int j = 0; j < 8; j++) ses[c*8 + j] = mask_f*acc[j];
    }
    __syncthreads();

    const float bmu_f  = IO<B>::ld(bmu, n);
    const float blv_f  = IO<B>::ld(blv, n);
    const float waff_f = IO<B>::ld(waff, n);
    const float baff_f = IO<B>::ld(baff, n);

    const int t0 = tid*8;
    float xf[40], xs[40];
    #pragma unroll
    for (int i = 0; i < 10; i++){
        float4 a = *(const float4*)&frs[t0 + 4*i];
        xf[4*i]=a.x; xf[4*i+1]=a.y; xf[4*i+2]=a.z; xf[4*i+3]=a.w;
        float4 b = *(const float4*)&ses[t0 + 4*i];
        xs[4*i]=b.x; xs[4*i+1]=b.y; xs[4*i+2]=b.z; xs[4*i+3]=b.w;
    }

    float aMu[8], aLv[8];
    #pragma unroll
    for (int j = 0; j < 8; j++){ aMu[j]=bmu_f; aLv[j]=blv_f; }
    #pragma unroll
    for (int k = 0; k < Kk; k++){
        float wf = wmf_s[k], wsn = wms_s[k], vf = wlf_s[k], vsn = wls_s[k];
        #pragma unroll
        for (int j = 0; j < 8; j++){
            aMu[j] = fmaf(xf[j+k], wf, fmaf(xs[j+k], wsn, aMu[j]));
            aLv[j] = fmaf(xf[j+k], vf, fmaf(xs[j+k], vsn, aLv[j]));
        }
    }

    const size_t base = (size_t)n*Tt + t0;
    float ev[8];
    IO<B>::ld8(eps, base, ev);

    float smp[8], cav[8], siv[8];
    #pragma unroll
    for (int j = 0; j < 8; j++){
        float s = aMu[j] + expf(0.5f*aLv[j])*ev[j];
        smp[j] = s;
        float x = waff_f*s + baff_f;
        cav[j] = (x > 20.f) ? x : log1pf(expf(x));
        siv[j] = ses[t0 + j + 16];   // crop = 16
    }

    IO<B>::st8(region<B>(outv,2), base, aMu);
    IO<B>::st8(region<B>(outv,3), base, aLv);
    IO<B>::st8(region<B>(outv,4), base, smp);
    IO<B>::st8(region<B>(outv,5), base, cav);
    IO<B>::st8(region<B>(outv,8), base, siv);
}

__global__ __launch_bounds__(256) void kA(
    const void* fr, const void* odor, const void* eps,
    const void* Wenc, const void* benc, const void* mask,
    const void* Wmf, const void* Wms, const void* bmu,
    const void* Wlf, const void* Wls, const void* blv,
    const void* waff, const void* baff, void* outv)
{
    __shared__ float frs[TEx];
    __shared__ float ses[TEx];
    __shared__ float wv[4*Kk + ODOR];
    if (detect_bf16(eps))
        bodyA<true >(fr,odor,eps,Wenc,benc,mask,Wmf,Wms,bmu,Wlf,Wls,blv,waff,baff,outv,frs,ses,wv);
    else
        bodyA<false>(fr,odor,eps,Wenc,benc,mask,Wmf,Wms,bmu,Wlf,Wls,blv,waff,baff,outv,frs,ses,wv);
}

// ---------------- old scalar kB (f32 fallback / small-ws fallback) ----------------
template<bool B>
__device__ void bodyB(const void* Wch, const void* Wel,
                      const void* bias, const void* tau, void* outv,
                      int tx, int ty, int bx, int by)
{
    const int t  = bx*64 + tx;
    const int n0 = by*32;

    const void* o_sv = region<B>(outv, 4);
    const void* o_si = region<B>(outv, 8);
    void* o_mnv = region<B>(outv, 0);
    void* o_rec = region<B>(outv, 7);

    int nn[8]; size_t pb[8]; float acc[8];
    #pragma unroll
    for (int r = 0; r < 8; r++){
        int v = n0 + ty + 4*r;
        nn[r] = v;
        int c = (v < Nn) ? v : 0;
        pb[r] = (size_t)c * 151;
        acc[r] = 0.f;
    }

    for (int mh = 0; mh < 151; mh++){
        const int m = mh*2;
        float s0 = IO<B>::ld(o_sv, (size_t)m*Tt + t);
        float s1 = IO<B>::ld(o_sv, (size_t)(m+1)*Tt + t);
        float a0 = fmaxf(s0, 0.f), a1 = fmaxf(s1, 0.f);
        #pragma unroll
        for (int r = 0; r < 8; r++){
            float2 wc = IO<B>::ld2(Wch, pb[r] + mh);
            float2 we = IO<B>::ld2(Wel, pb[r] + mh);
            acc[r] = fmaf(wc.x, a0, acc[r]);
            acc[r] = fmaf(wc.y, a1, acc[r]);
            acc[r] = fmaf(we.x, s0, acc[r]);
            acc[r] = fmaf(we.y, s1, acc[r]);
        }
    }

    #pragma unroll
    for (int r = 0; r < 8; r++){
        if (nn[r] < Nn){
            const size_t idx = (size_t)nn[r]*Tt + t;
            float si  = IO<B>::ld(o_si, idx);
            float rec = acc[r] + si;
            IO<B>::st(o_rec, idx, rec);
            float sv = IO<B>::ld(o_sv, idx);
            float ta = IO<B>::ld(tau, nn[r]);
            float bi = IO<B>::ld(bias, nn[r]);
            IO<B>::st(o_mnv, idx, sv + (DTc/ta)*(-sv + rec + bi));
        }
    }
}

__global__ __launch_bounds__(256) void kB(
    const void* Wch, const void* Wel, const void* bias, const void* tau,
    const void* eps, void* outv)
{
    int tx = threadIdx.x & 63, ty = threadIdx.x >> 6;
    if (detect_bf16(eps)) bodyB<true >(Wch, Wel, bias, tau, outv, tx, ty, blockIdx.x, blockIdx.y);
    else                  bodyB<false>(Wch, Wel, bias, tau, outv, tx, ty, blockIdx.x, blockIdx.y);
}

// ---------------- Kernel P: pack W_cat = [W_chem | W_elec] (MW x KX bf16) ----------------
__global__ __launch_bounds__(256) void kP(
    const void* Wch, const void* Wel, const void* eps, unsigned short* __restrict__ wcat)
{
    if (!detect_bf16(eps)) return;
    const unsigned short* wc = (const unsigned short*)Wch;
    const unsigned short* we = (const unsigned short*)Wel;
    const int m = blockIdx.x;                 // 0..303
    for (int k = threadIdx.x; k < KX; k += 256){
        unsigned short v = 0;
        if (m < Nn){
            if (k < Nn)                 v = wc[(size_t)m*Nn + k];
            else if (k >= 320 && k < 320 + Nn) v = we[(size_t)m*Nn + (k - 320)];
        }
        wcat[(size_t)m*KX + k] = v;
    }
}

// ---------------- Kernel T: X^T (2048 x KX bf16): cols [0,320)=relu(sv), [320,640)=sv ----
__global__ __launch_bounds__(256) void kT(
    const void* eps, void* outv, unsigned short* __restrict__ xt)
{
    if (!detect_bf16(eps)) return;
    __shared__ unsigned short tile[64][68];
    const unsigned short* o_sv = (const unsigned short*)region<true>(outv, 4);
    const int t0 = blockIdx.x*64;             // 32 tiles
    const int m0 = blockIdx.y*64;             // 5 tiles (covers 0..319)
    const int tid = threadIdx.x;
    const int c = tid & 7, r0 = tid >> 3;     // r0: 0..31

    #pragma unroll
    for (int h = 0; h < 2; h++){
        const int r = r0 + 32*h;
        const int m = m0 + r;
        uint4 u = make_uint4(0,0,0,0);
        if (m < Nn) u = *(const uint4*)(o_sv + (size_t)m*Tt + t0 + c*8);
        unsigned short* d = &tile[r][c*8];
        d[0]=(unsigned short)(u.x&0xFFFF); d[1]=(unsigned short)(u.x>>16);
        d[2]=(unsigned short)(u.y&0xFFFF); d[3]=(unsigned short)(u.y>>16);
        d[4]=(unsigned short)(u.z&0xFFFF); d[5]=(unsigned short)(u.z>>16);
        d[6]=(unsigned short)(u.w&0xFFFF); d[7]=(unsigned short)(u.w>>16);
    }
    __syncthreads();

    #pragma unroll
    for (int h = 0; h < 2; h++){
        const int tr = r0 + 32*h;
        const int t = t0 + tr;
        unsigned short sv[8], av[8];
        #pragma unroll
        for (int j = 0; j < 8; j++){
            unsigned short u = tile[c*8 + j][tr];
            sv[j] = u;
            av[j] = (u & 0x8000u) ? (unsigned short)0 : u;   // relu on bf16 bits
        }
        uint4 usv = make_uint4((unsigned)sv[0]|((unsigned)sv[1]<<16),
                               (unsigned)sv[2]|((unsigned)sv[3]<<16),
                               (unsigned)sv[4]|((unsigned)sv[5]<<16),
                               (unsigned)sv[6]|((unsigned)sv[7]<<16));
        uint4 uav = make_uint4((unsigned)av[0]|((unsigned)av[1]<<16),
                               (unsigned)av[2]|((unsigned)av[3]<<16),
                               (unsigned)av[4]|((unsigned)av[5]<<16),
                               (unsigned)av[6]|((unsigned)av[7]<<16));
        *(uint4*)(xt + (size_t)t*KX + m0 + c*8)       = uav;
        *(uint4*)(xt + (size_t)t*KX + 320 + m0 + c*8) = usv;
    }
}

// ---------------- Kernel G: MFMA GEMM + epilogue ----------------
// grid (32 n-tiles, 19 m-tiles), 256 threads = 4 waves; wave does 16x16 C tile.
__device__ void bodyG(const unsigned short* __restrict__ wcat,
                      const unsigned short* __restrict__ xt,
                      const void* bias, const void* tau, void* outv)
{
    const int tid = threadIdx.x;
    const int wave = tid >> 6, lane = tid & 63;
    const int ln = lane & 15, quad = lane >> 4;
    const int n_base = blockIdx.x*64 + wave*16;   // t
    const int m_base = blockIdx.y*16;             // neuron

    const unsigned short* Ap = wcat + (size_t)(m_base + ln)*KX + quad*8;
    const unsigned short* Bp = xt   + (size_t)(n_base + ln)*KX + quad*8;

    f32x4 acc = {0.f, 0.f, 0.f, 0.f};
    #pragma unroll
    for (int kb = 0; kb < KX/32; kb++){
        short8 a = *(const short8*)(Ap + kb*32);
        short8 b = *(const short8*)(Bp + kb*32);
        acc = __builtin_amdgcn_mfma_f32_16x16x32_bf16(a, b, acc, 0, 0, 0);
    }

    const void* o_sv = region<true>(outv, 4);
    const void* o_si = region<true>(outv, 8);
    void* o_mnv = region<true>(outv, 0);
    void* o_rec = region<true>(outv, 7);

    const int t = n_base + ln;
    #pragma unroll
    for (int r = 0; r < 4; r++){
        const int neuron = m_base + quad*4 + r;
        if (neuron < Nn){
            const size_t idx = (size_t)neuron*Tt + t;
            float si  = IO<true>::ld(o_si, idx);
            float rec = acc[r] + si;
            IO<true>::st(o_rec, idx, rec);
            float sv = IO<true>::ld(o_sv, idx);
            float ta = IO<true>::ld(tau, neuron);
            float bi = IO<true>::ld(bias, neuron);
            IO<true>::st(o_mnv, idx, sv + (DTc/ta)*(-sv + rec + bi));
        }
    }
}

__global__ __launch_bounds__(256) void kG(
    const unsigned short* wcat, const unsigned short* xt,
    const void* Wch, const void* Wel,
    const void* bias, const void* tau, const void* eps, void* outv)
{
    if (detect_bf16(eps)){
        bodyG(wcat, xt, bias, tau, outv);
    } else {
        if (blockIdx.y < 10){
            int tx = threadIdx.x & 63, ty = threadIdx.x >> 6;
            bodyB<false>(Wch, Wel, bias, tau, outv, tx, ty, blockIdx.x, blockIdx.y);
        }
    }
}

// ---------------- Kernel C: calcium IIR scan ----------------
template<bool B>
__device__ void bodyC(const void* fft, const void* scale, const void* shift,
                      const void* ctau, void* outv, float* Bs, float* Ps)
{
    const int n = blockIdx.x;
    const int tid = threadIdx.x;
    const void* o_ca = region<B>(outv, 5);
    void* o_fl = region<B>(outv, 1);
    void* o_mc = region<B>(outv, 6);

    const float sc = IO<B>::ld(scale, n);
    const float sh = IO<B>::ld(shift, n);
    const float ct = IO<B>::ld(ctau, n);
    const float decay = expf(-DTc/ct);

    const int t0 = tid*8;
    const size_t base = (size_t)n*Tt + t0;
    float x[8];
    IO<B>::ld8(o_ca, base, x);

    float b = 0.f;
    #pragma unroll
    for (int j = 0; j < 8; j++) b = fmaf(decay, b, x[j]);
    Bs[tid] = b;
    __syncthreads();

    if (tid == 0){
        const float init = (IO<B>::ld(fft, (size_t)n*Tt) - sh)/sc;
        const float d2 = decay*decay, d4 = d2*d2, d8 = d4*d4;
        float P = init;
        for (int i = 0; i < 256; i++){ Ps[i] = P; P = fmaf(d8, P, Bs[i]); }
    }
    __syncthreads();

    float c = Ps[tid];
    float mc[8], fl[8];
    #pragma unroll
    for (int j = 0; j < 8; j++){
        c = fmaf(decay, c, x[j]);
        mc[j] = c;
        fl[j] = fmaf(sc, c, sh);
    }
    IO<B>::st8(o_mc, base, mc);
    IO<B>::st8(o_fl, base, fl);
}

__global__ __launch_bounds__(256) void kC(
    const void* fft, const void* scale, const void* shift, const void* ctau,
    const void* eps, void* outv)
{
    __shared__ float Bs[256];
    __shared__ float Ps[256];
    if (detect_bf16(eps)) bodyC<true >(fft, scale, shift, ctau, outv, Bs, Ps);
    else                  bodyC<false>(fft, scale, shift, ctau, outv, Bs, Ps);
}

extern "C" void kernel_launch(void* const* d_in, const int* in_sizes, int n_in,
                              void* d_out, int out_size, void* d_ws, size_t ws_size,
                              hipStream_t stream) {
    const void* fr   = d_in[0];
    const void* fft  = d_in[1];
    const void* odor = d_in[2];
    const void* eps  = d_in[3];
    const void* Wenc = d_in[4];
    const void* benc = d_in[5];
    const void* mask = d_in[6];
    const void* Wmf  = d_in[7];
    const void* Wms  = d_in[8];
    const void* bmu  = d_in[9];
    const void* Wlf  = d_in[10];
    const void* Wls  = d_in[11];
    const void* blv  = d_in[12];
    const void* Wch  = d_in[13];
    const void* Wel  = d_in[14];
    const void* bias = d_in[15];
    const void* tau  = d_in[16];
    const void* waff = d_in[17];
    const void* baff = d_in[18];
    const void* scal = d_in[19];
    const void* shft = d_in[20];
    const void* ctau = d_in[21];

    kA<<<Nn, 256, 0, stream>>>(fr, odor, eps, Wenc, benc, mask, Wmf, Wms, bmu,
                               Wlf, Wls, blv, waff, baff, d_out);

    const size_t WS_NEED = (size_t)Tt*KX*2 + (size_t)MW*KX*2;
    if (ws_size >= WS_NEED){
        unsigned short* xt   = (unsigned short*)d_ws;
        unsigned short* wcat = xt + (size_t)Tt*KX;
        kP<<<MW, 256, 0, stream>>>(Wch, Wel, eps, wcat);
        kT<<<dim3(32, 5), 256, 0, stream>>>(eps, d_out, xt);
        kG<<<dim3(32, 19), 256, 0, stream>>>(wcat, xt, Wch, Wel, bias, tau, eps, d_out);
    } else {
        kB<<<dim3(32, 10), 256, 0, stream>>>(Wch, Wel, bias, tau, eps, d_out);
    }

    kC<<<Nn, 256, 0, stream>>>(fft, scal, shft, ctau, eps, d_out);
}

// Round 6
// 152.044 us; speedup vs baseline: 1.9195x; 1.9101x over previous
//
#include <hip/hip_runtime.h>
#include <hip/hip_bf16.h>

#define Nn 302
#define Tt 2048
#define TEx 2080
#define Kk 33
#define ODOR 16
#define DTc 0.2f
#define NT (Nn*Tt)
// GEMM: C[m,t] = sum_k Wcat[m,k] * X[k,t]; K = 640 (relu(sv) k<320, raw sv k>=320)
#define NKB 20          // K chunks of 32
#define NMT 19          // m tiles of 16 (304 rows)
#define NNT 128         // t tiles of 16

typedef __attribute__((ext_vector_type(8))) short short8;
typedef __attribute__((ext_vector_type(4))) float f32x4;

__device__ __forceinline__ unsigned short f2bu(float x){ __hip_bfloat16 h = __float2bfloat16(x); unsigned short u; __builtin_memcpy(&u, &h, 2); return u; }

// ALL inputs/outputs are float32 (proven: R2/R3 passed running the f32 bodies).
__device__ __forceinline__ void ld8(const float* p, size_t i, float* v){
    float4 a = *(const float4*)(p + i);
    float4 b = *(const float4*)(p + i + 4);
    v[0]=a.x; v[1]=a.y; v[2]=a.z; v[3]=a.w;
    v[4]=b.x; v[5]=b.y; v[6]=b.z; v[7]=b.w;
}
__device__ __forceinline__ void st8(float* p, size_t i, const float* v){
    *(float4*)(p + i)     = make_float4(v[0],v[1],v[2],v[3]);
    *(float4*)(p + i + 4) = make_float4(v[4],v[5],v[6],v[7]);
}

// out regions (x NT f32): 0 mnv, 1 fluor, 2 mu_v, 3 logvar, 4 sample_v,
// 5 calcium_act, 6 mu_calcium, 7 recurrent_in, 8 sensory_input
__device__ __forceinline__ float* region(void* outv, int r){
    return (float*)outv + (size_t)r * NT;
}

// ============ Kernel A: encode + dwconv + pointwise + fused calcium scan ============
__global__ __launch_bounds__(256) void kA(
    const float* __restrict__ fr, const float* __restrict__ odor,
    const float* __restrict__ eps,
    const float* __restrict__ Wenc, const float* __restrict__ benc,
    const float* __restrict__ mask,
    const float* __restrict__ Wmf, const float* __restrict__ Wms,
    const float* __restrict__ bmu,
    const float* __restrict__ Wlf, const float* __restrict__ Wls,
    const float* __restrict__ blv,
    const float* __restrict__ waff, const float* __restrict__ baff,
    const float* __restrict__ fft, const float* __restrict__ scal,
    const float* __restrict__ shft, const float* __restrict__ ctau,
    void* outv)
{
    __shared__ float frs[TEx];
    __shared__ float ses[TEx];
    __shared__ float Bsc[256];
    __shared__ float Psc[256];
    __shared__ float wv[4*Kk + ODOR];

    const int n = blockIdx.x;
    const int tid = threadIdx.x;
    float* wmf_s = wv;        float* wms_s = wv + Kk;
    float* wlf_s = wv + 2*Kk; float* wls_s = wv + 3*Kk;
    float* wenc_s = wv + 4*Kk;

    if (tid < Kk){
        wmf_s[tid] = Wmf[n*Kk+tid];
        wms_s[tid] = Wms[n*Kk+tid];
        wlf_s[tid] = Wlf[n*Kk+tid];
        wls_s[tid] = Wls[n*Kk+tid];
    }
    if (tid < ODOR) wenc_s[tid] = Wenc[n*ODOR+tid];

    for (int c = tid; c < TEx/8; c += 256){
        float v[8];
        ld8(fr, (size_t)n*TEx + c*8, v);
        #pragma unroll
        for (int j = 0; j < 8; j++) frs[c*8+j] = v[j];
    }
    __syncthreads();

    const float benc_f = benc[n];
    const float mask_f = mask[n];
    for (int c = tid; c < TEx/8; c += 256){
        float acc[8];
        #pragma unroll
        for (int j = 0; j < 8; j++) acc[j] = benc_f;
        #pragma unroll
        for (int o = 0; o < ODOR; o++){
            float v[8];
            ld8(odor, (size_t)o*TEx + c*8, v);
            #pragma unroll
            for (int j = 0; j < 8; j++) acc[j] = fmaf(wenc_s[o], v[j], acc[j]);
        }
        #pragma unroll
        for (int j = 0; j < 8; j++) ses[c*8+j] = mask_f*acc[j];
    }
    __syncthreads();

    const float bmu_f  = bmu[n];
    const float blv_f  = blv[n];
    const float waff_f = waff[n];
    const float baff_f = baff[n];

    const int t0 = tid*8;
    float xf[40], xs[40];
    #pragma unroll
    for (int i = 0; i < 10; i++){
        float4 a = *(const float4*)&frs[t0 + 4*i];
        xf[4*i]=a.x; xf[4*i+1]=a.y; xf[4*i+2]=a.z; xf[4*i+3]=a.w;
        float4 b = *(const float4*)&ses[t0 + 4*i];
        xs[4*i]=b.x; xs[4*i+1]=b.y; xs[4*i+2]=b.z; xs[4*i+3]=b.w;
    }

    float aMu[8], aLv[8];
    #pragma unroll
    for (int j = 0; j < 8; j++){ aMu[j]=bmu_f; aLv[j]=blv_f; }
    #pragma unroll
    for (int k = 0; k < Kk; k++){
        float wf=wmf_s[k], wsn=wms_s[k], vf=wlf_s[k], vsn=wls_s[k];
        #pragma unroll
        for (int j = 0; j < 8; j++){
            aMu[j] = fmaf(xf[j+k], wf, fmaf(xs[j+k], wsn, aMu[j]));
            aLv[j] = fmaf(xf[j+k], vf, fmaf(xs[j+k], vsn, aLv[j]));
        }
    }

    const size_t base = (size_t)n*Tt + t0;
    float ev[8];
    ld8(eps, base, ev);

    float smp[8], cav[8], siv[8];
    #pragma unroll
    for (int j = 0; j < 8; j++){
        float s = aMu[j] + expf(0.5f*aLv[j])*ev[j];
        smp[j] = s;
        float x = waff_f*s + baff_f;
        cav[j] = (x > 20.f) ? x : log1pf(expf(x));
        siv[j] = ses[t0 + j + 16];   // crop = 16
    }

    st8(region(outv,2), base, aMu);
    st8(region(outv,3), base, aLv);
    st8(region(outv,4), base, smp);
    st8(region(outv,5), base, cav);
    st8(region(outv,8), base, siv);

    // ---- calcium IIR scan: c[-1]=init, c[t]=decay*c[t-1]+ca[t] ----
    const float sc = scal[n];
    const float sh = shft[n];
    const float ct = ctau[n];
    const float decay = expf(-DTc/ct);

    float b = 0.f;
    #pragma unroll
    for (int j = 0; j < 8; j++) b = fmaf(decay, b, cav[j]);
    Bsc[tid] = b;
    __syncthreads();

    if (tid == 0){
        const float init = (fft[(size_t)n*Tt] - sh)/sc;
        const float d2 = decay*decay, d4 = d2*d2, d8 = d4*d4;
        float P = init;
        for (int i = 0; i < 256; i++){ Psc[i] = P; P = fmaf(d8, P, Bsc[i]); }
    }
    __syncthreads();

    float c = Psc[tid];
    float mc[8], fl[8];
    #pragma unroll
    for (int j = 0; j < 8; j++){
        c = fmaf(decay, c, cav[j]);
        mc[j] = c;
        fl[j] = fmaf(sc, c, sh);
    }
    st8(region(outv,6), base, mc);
    st8(region(outv,1), base, fl);
}

// ============ Kernel TP: build bf16 fragment-swizzled GEMM operands in d_ws ============
// frag(tile, kb, lane l) = 8 bf16 at ((tile*NKB + kb)*64 + l)*8.
//   A: Wcat[tile*16 + (l&15)][kb*32 + (l>>4)*8 + j]
//   B: X[kb*32 + (l>>4)*8 + j][tile*16 + (l&15)], X[k<320]=relu(sv[k]), X[k>=320]=sv[k-320]
__global__ __launch_bounds__(256) void kTP(
    const float* __restrict__ Wch, const float* __restrict__ Wel,
    void* outv, unsigned short* __restrict__ xt_sw, unsigned short* __restrict__ wc_sw)
{
    __shared__ unsigned short tile[64][68];
    const int blk = blockIdx.x;
    const int tid = threadIdx.x;

    if (blk >= 160){
        const int mt = blk - 160;              // 0..NMT-1
        for (int i = 0; i < 5; i++){
            const int fid = tid + 256*i;
            const int kb = fid >> 6, l = fid & 63;
            const int ln = l & 15, quad = l >> 4;
            const int m = mt*16 + ln;
            const int k0 = kb*32 + quad*8;
            unsigned short v[8];
            #pragma unroll
            for (int j = 0; j < 8; j++){
                const int k = k0 + j;
                float x = 0.f;
                if (m < Nn){
                    if (k < Nn)                      x = Wch[(size_t)m*Nn + k];
                    else if (k >= 320 && k < 320+Nn) x = Wel[(size_t)m*Nn + (k-320)];
                }
                v[j] = f2bu(x);
            }
            *(uint4*)(wc_sw + ((size_t)(mt*NKB + kb)*64 + l)*8) =
                make_uint4((unsigned)v[0]|((unsigned)v[1]<<16), (unsigned)v[2]|((unsigned)v[3]<<16),
                           (unsigned)v[4]|((unsigned)v[5]<<16), (unsigned)v[6]|((unsigned)v[7]<<16));
        }
        return;
    }

    // ---- transpose branch: sv rows [m0, m0+64) x t cols [t0, t0+64) ----
    const float* o_sv = region(outv, 4);
    const int bx = blk & 31;
    const int m0 = (blk >> 5) * 64;            // 0,64,128,192,256
    const int t0 = bx*64;
    const int c = tid & 7, r0 = tid >> 3;

    #pragma unroll
    for (int h = 0; h < 2; h++){
        const int r = r0 + 32*h;
        const int m = m0 + r;
        float v[8] = {0,0,0,0,0,0,0,0};
        if (m < Nn) ld8(o_sv, (size_t)m*Tt + t0 + c*8, v);
        unsigned short* d = &tile[r][c*8];
        #pragma unroll
        for (int j = 0; j < 8; j++) d[j] = f2bu(v[j]);
    }
    __syncthreads();

    const int kb0 = m0 >> 5;
    #pragma unroll
    for (int i = 0; i < 2; i++){
        const int fid = tid + 256*i;           // 0..511
        const int nt_loc = fid >> 7;           // 0..3
        const int kb_loc = (fid >> 6) & 1;     // 0..1
        const int l  = fid & 63;
        const int ln = l & 15, quad = l >> 4;
        const int nt = bx*4 + nt_loc;
        unsigned short sv[8], av[8];
        #pragma unroll
        for (int j = 0; j < 8; j++){
            unsigned short u = tile[kb_loc*32 + quad*8 + j][nt_loc*16 + ln];
            sv[j] = u;
            av[j] = (u & 0x8000u) ? (unsigned short)0 : u;   // relu on bf16 bits
        }
        *(uint4*)(xt_sw + ((size_t)(nt*NKB + kb0 + kb_loc)*64 + l)*8) =
            make_uint4((unsigned)av[0]|((unsigned)av[1]<<16), (unsigned)av[2]|((unsigned)av[3]<<16),
                       (unsigned)av[4]|((unsigned)av[5]<<16), (unsigned)av[6]|((unsigned)av[7]<<16));
        *(uint4*)(xt_sw + ((size_t)(nt*NKB + 10 + kb0 + kb_loc)*64 + l)*8) =
            make_uint4((unsigned)sv[0]|((unsigned)sv[1]<<16), (unsigned)sv[2]|((unsigned)sv[3]<<16),
                       (unsigned)sv[4]|((unsigned)sv[5]<<16), (unsigned)sv[6]|((unsigned)sv[7]<<16));
    }
}

// ============ Kernel G: MFMA GEMM on swizzled frags + f32 epilogue ============
// grid (32, NMT): 4 waves/block, wave w -> nt = bx*4+w, mt = by.
__global__ __launch_bounds__(256) void kG(
    const unsigned short* __restrict__ wc_sw, const unsigned short* __restrict__ xt_sw,
    const float* __restrict__ bias, const float* __restrict__ tau,
    void* outv)
{
    __shared__ float C[16][68];
    const int tid = threadIdx.x;
    const int wave = tid >> 6, lane = tid & 63;
    const int ln = lane & 15, quad = lane >> 4;
    const int bx = blockIdx.x, by = blockIdx.y;
    const int nt = bx*4 + wave;

    const unsigned short* Ap = wc_sw + (size_t)by*NKB*512 + lane*8;
    const unsigned short* Bp = xt_sw + (size_t)nt*NKB*512 + lane*8;

    f32x4 acc = {0.f,0.f,0.f,0.f};
    #pragma unroll
    for (int kb = 0; kb < NKB; kb++){
        short8 a = *(const short8*)(Ap + kb*512);
        short8 b = *(const short8*)(Bp + kb*512);
        acc = __builtin_amdgcn_mfma_f32_16x16x32_bf16(a, b, acc, 0, 0, 0);
    }

    #pragma unroll
    for (int r = 0; r < 4; r++) C[quad*4 + r][wave*16 + ln] = acc[r];
    __syncthreads();

    if (tid < 128){
        const int m_loc = tid >> 3, strip = tid & 7;
        const int m = by*16 + m_loc;
        if (m < Nn){
            const float* o_sv = region(outv, 4);
            const float* o_si = region(outv, 8);
            float* o_mnv = region(outv, 0);
            float* o_rec = region(outv, 7);
            const int t = bx*64 + strip*8;
            const size_t idx = (size_t)m*Tt + t;
            float si[8], sv[8], rec[8], mnv[8];
            ld8(o_si, idx, si);
            ld8(o_sv, idx, sv);
            const float it = DTc / tau[m];
            const float bi = bias[m];
            #pragma unroll
            for (int j = 0; j < 8; j++){
                float rc = C[m_loc][strip*8 + j] + si[j];
                rec[j] = rc;
                mnv[j] = sv[j] + it*(-sv[j] + rc + bi);
            }
            st8(o_rec, idx, rec);
            st8(o_mnv, idx, mnv);
        }
    }
}

// ============ scalar f32 fallback GEMM (R2/R3-proven; only if ws too small) ============
__global__ __launch_bounds__(256) void kBs(
    const float* __restrict__ Wch, const float* __restrict__ Wel,
    const float* __restrict__ bias, const float* __restrict__ tau,
    void* outv)
{
    const int tx = threadIdx.x & 63, ty = threadIdx.x >> 6;
    const int t  = blockIdx.x*64 + tx;
    const int n0 = blockIdx.y*32;

    const float* o_sv = region(outv, 4);
    const float* o_si = region(outv, 8);
    float* o_mnv = region(outv, 0);
    float* o_rec = region(outv, 7);

    int nn[8]; size_t pb[8]; float acc[8];
    #pragma unroll
    for (int r = 0; r < 8; r++){
        int v = n0 + ty + 4*r;
        nn[r] = v;
        pb[r] = (size_t)((v < Nn) ? v : 0) * 151;
        acc[r] = 0.f;
    }
    for (int mh = 0; mh < 151; mh++){
        const int m = mh*2;
        float s0 = o_sv[(size_t)m*Tt + t];
        float s1 = o_sv[(size_t)(m+1)*Tt + t];
        float a0 = fmaxf(s0,0.f), a1 = fmaxf(s1,0.f);
        #pragma unroll
        for (int r = 0; r < 8; r++){
            float2 wc = ((const float2*)Wch)[pb[r] + mh];
            float2 we = ((const float2*)Wel)[pb[r] + mh];
            acc[r] = fmaf(wc.x, a0, acc[r]);
            acc[r] = fmaf(wc.y, a1, acc[r]);
            acc[r] = fmaf(we.x, s0, acc[r]);
            acc[r] = fmaf(we.y, s1, acc[r]);
        }
    }
    #pragma unroll
    for (int r = 0; r < 8; r++){
        if (nn[r] < Nn){
            const size_t idx = (size_t)nn[r]*Tt + t;
            float rec = acc[r] + o_si[idx];
            o_rec[idx] = rec;
            float sv = o_sv[idx];
            o_mnv[idx] = sv + (DTc/tau[nn[r]])*(-sv + rec + bias[nn[r]]);
        }
    }
}

extern "C" void kernel_launch(void* const* d_in, const int* in_sizes, int n_in,
                              void* d_out, int out_size, void* d_ws, size_t ws_size,
                              hipStream_t stream) {
    const float* fr   = (const float*)d_in[0];
    const float* fft  = (const float*)d_in[1];
    const float* odor = (const float*)d_in[2];
    const float* eps  = (const float*)d_in[3];
    const float* Wenc = (const float*)d_in[4];
    const float* benc = (const float*)d_in[5];
    const float* mask = (const float*)d_in[6];
    const float* Wmf  = (const float*)d_in[7];
    const float* Wms  = (const float*)d_in[8];
    const float* bmu  = (const float*)d_in[9];
    const float* Wlf  = (const float*)d_in[10];
    const float* Wls  = (const float*)d_in[11];
    const float* blv  = (const float*)d_in[12];
    const float* Wch  = (const float*)d_in[13];
    const float* Wel  = (const float*)d_in[14];
    const float* bias = (const float*)d_in[15];
    const float* tau  = (const float*)d_in[16];
    const float* waff = (const float*)d_in[17];
    const float* baff = (const float*)d_in[18];
    const float* scal = (const float*)d_in[19];
    const float* shft = (const float*)d_in[20];
    const float* ctau = (const float*)d_in[21];

    kA<<<Nn, 256, 0, stream>>>(fr, odor, eps, Wenc, benc, mask, Wmf, Wms, bmu,
                               Wlf, Wls, blv, waff, baff, fft, scal, shft, ctau, d_out);

    const size_t XT_ELEMS = (size_t)NNT*NKB*64*8;                    // 1,310,720 u16
    const size_t WS_NEED  = (XT_ELEMS + (size_t)NMT*NKB*64*8) * 2;   // 3,010,560 B (proven fit)
    if (ws_size >= WS_NEED){
        unsigned short* xt_sw = (unsigned short*)d_ws;
        unsigned short* wc_sw = xt_sw + XT_ELEMS;
        kTP<<<160 + NMT, 256, 0, stream>>>(Wch, Wel, d_out, xt_sw, wc_sw);
        kG<<<dim3(32, NMT), 256, 0, stream>>>(wc_sw, xt_sw, bias, tau, d_out);
    } else {
        kBs<<<dim3(32, 10), 256, 0, stream>>>(Wch, Wel, bias, tau, d_out);
    }
}

// Round 7
// 151.202 us; speedup vs baseline: 1.9302x; 1.0056x over previous
//
#include <hip/hip_runtime.h>
#include <hip/hip_bf16.h>

#define Nn 302
#define Tt 2048
#define TEx 2080
#define Kk 33
#define ODOR 16
#define DTc 0.2f
#define NT (Nn*Tt)
// GEMM: C[m,t] = sum_k Wcat[m,k] * X[k,t]; K = 640 (relu(sv) k<320, raw sv k>=320)
#define NKB 20          // K chunks of 32
#define NMT 19          // m tiles of 16 (304 rows)
#define NNT 128         // t tiles of 16

typedef __attribute__((ext_vector_type(8))) short short8;
typedef __attribute__((ext_vector_type(4))) float f32x4;

__device__ __forceinline__ unsigned short f2bu(float x){ __hip_bfloat16 h = __float2bfloat16(x); unsigned short u; __builtin_memcpy(&u, &h, 2); return u; }

// ALL inputs/outputs are float32 (proven: R2/R3/R6 passed running f32 bodies).
__device__ __forceinline__ void ld8(const float* p, size_t i, float* v){
    float4 a = *(const float4*)(p + i);
    float4 b = *(const float4*)(p + i + 4);
    v[0]=a.x; v[1]=a.y; v[2]=a.z; v[3]=a.w;
    v[4]=b.x; v[5]=b.y; v[6]=b.z; v[7]=b.w;
}
__device__ __forceinline__ void st8(float* p, size_t i, const float* v){
    *(float4*)(p + i)     = make_float4(v[0],v[1],v[2],v[3]);
    *(float4*)(p + i + 4) = make_float4(v[4],v[5],v[6],v[7]);
}

// out regions (x NT f32): 0 mnv, 1 fluor, 2 mu_v, 3 logvar, 4 sample_v,
// 5 calcium_act, 6 mu_calcium, 7 recurrent_in, 8 sensory_input
__device__ __forceinline__ float* region(void* outv, int r){
    return (float*)outv + (size_t)r * NT;
}

// ============ Kernel A: encode + dwconv + pointwise + fused calcium scan ============
__global__ __launch_bounds__(256) void kA(
    const float* __restrict__ fr, const float* __restrict__ odor,
    const float* __restrict__ eps,
    const float* __restrict__ Wenc, const float* __restrict__ benc,
    const float* __restrict__ mask,
    const float* __restrict__ Wmf, const float* __restrict__ Wms,
    const float* __restrict__ bmu,
    const float* __restrict__ Wlf, const float* __restrict__ Wls,
    const float* __restrict__ blv,
    const float* __restrict__ waff, const float* __restrict__ baff,
    const float* __restrict__ fft, const float* __restrict__ scal,
    const float* __restrict__ shft, const float* __restrict__ ctau,
    void* outv)
{
    __shared__ float frs[TEx];
    __shared__ float ses[TEx];
    __shared__ float Bsc[256];
    __shared__ float Psc[256];
    __shared__ float wv[4*Kk + ODOR];

    const int n = blockIdx.x;
    const int tid = threadIdx.x;
    float* wmf_s = wv;        float* wms_s = wv + Kk;
    float* wlf_s = wv + 2*Kk; float* wls_s = wv + 3*Kk;
    float* wenc_s = wv + 4*Kk;

    if (tid < Kk){
        wmf_s[tid] = Wmf[n*Kk+tid];
        wms_s[tid] = Wms[n*Kk+tid];
        wlf_s[tid] = Wlf[n*Kk+tid];
        wls_s[tid] = Wls[n*Kk+tid];
    }
    if (tid < ODOR) wenc_s[tid] = Wenc[n*ODOR+tid];

    for (int c = tid; c < TEx/8; c += 256){
        float v[8];
        ld8(fr, (size_t)n*TEx + c*8, v);
        #pragma unroll
        for (int j = 0; j < 8; j++) frs[c*8+j] = v[j];
    }
    __syncthreads();

    const float benc_f = benc[n];
    const float mask_f = mask[n];
    for (int c = tid; c < TEx/8; c += 256){
        float acc[8];
        #pragma unroll
        for (int j = 0; j < 8; j++) acc[j] = benc_f;
        #pragma unroll
        for (int o = 0; o < ODOR; o++){
            float v[8];
            ld8(odor, (size_t)o*TEx + c*8, v);
            #pragma unroll
            for (int j = 0; j < 8; j++) acc[j] = fmaf(wenc_s[o], v[j], acc[j]);
        }
        #pragma unroll
        for (int j = 0; j < 8; j++) ses[c*8+j] = mask_f*acc[j];
    }
    __syncthreads();

    const float bmu_f  = bmu[n];
    const float blv_f  = blv[n];
    const float waff_f = waff[n];
    const float baff_f = baff[n];

    const int t0 = tid*8;
    float xf[40], xs[40];
    #pragma unroll
    for (int i = 0; i < 10; i++){
        float4 a = *(const float4*)&frs[t0 + 4*i];
        xf[4*i]=a.x; xf[4*i+1]=a.y; xf[4*i+2]=a.z; xf[4*i+3]=a.w;
        float4 b = *(const float4*)&ses[t0 + 4*i];
        xs[4*i]=b.x; xs[4*i+1]=b.y; xs[4*i+2]=b.z; xs[4*i+3]=b.w;
    }

    float aMu[8], aLv[8];
    #pragma unroll
    for (int j = 0; j < 8; j++){ aMu[j]=bmu_f; aLv[j]=blv_f; }
    #pragma unroll
    for (int k = 0; k < Kk; k++){
        float wf=wmf_s[k], wsn=wms_s[k], vf=wlf_s[k], vsn=wls_s[k];
        #pragma unroll
        for (int j = 0; j < 8; j++){
            aMu[j] = fmaf(xf[j+k], wf, fmaf(xs[j+k], wsn, aMu[j]));
            aLv[j] = fmaf(xf[j+k], vf, fmaf(xs[j+k], vsn, aLv[j]));
        }
    }

    const size_t base = (size_t)n*Tt + t0;
    float ev[8];
    ld8(eps, base, ev);

    float smp[8], cav[8], siv[8];
    #pragma unroll
    for (int j = 0; j < 8; j++){
        float s = aMu[j] + expf(0.5f*aLv[j])*ev[j];
        smp[j] = s;
        float x = waff_f*s + baff_f;
        cav[j] = (x > 20.f) ? x : log1pf(expf(x));
        siv[j] = ses[t0 + j + 16];   // crop = 16
    }

    st8(region(outv,2), base, aMu);
    st8(region(outv,3), base, aLv);
    st8(region(outv,4), base, smp);
    st8(region(outv,5), base, cav);
    st8(region(outv,8), base, siv);

    // ---- calcium IIR scan: c[-1]=init, c[t]=decay*c[t-1]+ca[t] ----
    // thread chunk of 8 -> Bsc; wave 0 does a weighted Hillis-Steele scan over
    // 64 lanes x 4 chunks (factor d8 per chunk, d32 per lane).
    const float sc = scal[n];
    const float sh = shft[n];
    const float ct = ctau[n];
    const float decay = expf(-DTc/ct);

    float b = 0.f;
    #pragma unroll
    for (int j = 0; j < 8; j++) b = fmaf(decay, b, cav[j]);
    Bsc[tid] = b;
    __syncthreads();

    if (tid < 64){
        const float d2 = decay*decay, d4 = d2*d2, d8 = d4*d4;
        const float d16 = d8*d8, d32 = d16*d16;
        float g0=Bsc[4*tid], g1=Bsc[4*tid+1], g2=Bsc[4*tid+2], g3=Bsc[4*tid+3];
        float G = fmaf(d8, fmaf(d8, fmaf(d8, g0, g1), g2), g3);   // 32-elem block value
        float S = G, pw = d32;
        #pragma unroll
        for (int off = 1; off < 64; off <<= 1){
            float up = __shfl_up(S, off, 64);
            if (tid >= off) S = fmaf(pw, up, S);
            pw = pw*pw;
        }
        float E = __shfl_up(S, 1, 64);                            // exclusive prefix
        if (tid == 0) E = 0.f;
        const float init = (fft[(size_t)n*Tt] - sh)/sc;
        float P = fmaf(init, __powf(d32, (float)tid), E);         // carry entering chunk 4*tid
        #pragma unroll
        for (int j = 0; j < 4; j++){ Psc[4*tid+j] = P; P = fmaf(d8, P, Bsc[4*tid+j]); }
    }
    __syncthreads();

    float c = Psc[tid];
    float mc[8], fl[8];
    #pragma unroll
    for (int j = 0; j < 8; j++){
        c = fmaf(decay, c, cav[j]);
        mc[j] = c;
        fl[j] = fmaf(sc, c, sh);
    }
    st8(region(outv,6), base, mc);
    st8(region(outv,1), base, fl);
}

// ============ Kernel TP: build bf16 fragment-swizzled GEMM operands in d_ws ============
// frag(tile, kb, lane l) = 8 bf16 at ((tile*NKB + kb)*64 + l)*8.
//   A: Wcat[tile*16 + (l&15)][kb*32 + (l>>4)*8 + j]
//   B: X[kb*32 + (l>>4)*8 + j][tile*16 + (l&15)], X[k<320]=relu(sv[k]), X[k>=320]=sv[k-320]
__global__ __launch_bounds__(256) void kTP(
    const float* __restrict__ Wch, const float* __restrict__ Wel,
    void* outv, unsigned short* __restrict__ xt_sw, unsigned short* __restrict__ wc_sw)
{
    __shared__ unsigned short tile[64][68];
    const int blk = blockIdx.x;
    const int tid = threadIdx.x;

    if (blk >= 160){
        const int mt = blk - 160;              // 0..NMT-1
        for (int i = 0; i < 5; i++){
            const int fid = tid + 256*i;
            const int kb = fid >> 6, l = fid & 63;
            const int ln = l & 15, quad = l >> 4;
            const int m = mt*16 + ln;
            const int k0 = kb*32 + quad*8;
            unsigned short v[8];
            #pragma unroll
            for (int j = 0; j < 8; j++){
                const int k = k0 + j;
                float x = 0.f;
                if (m < Nn){
                    if (k < Nn)                      x = Wch[(size_t)m*Nn + k];
                    else if (k >= 320 && k < 320+Nn) x = Wel[(size_t)m*Nn + (k-320)];
                }
                v[j] = f2bu(x);
            }
            *(uint4*)(wc_sw + ((size_t)(mt*NKB + kb)*64 + l)*8) =
                make_uint4((unsigned)v[0]|((unsigned)v[1]<<16), (unsigned)v[2]|((unsigned)v[3]<<16),
                           (unsigned)v[4]|((unsigned)v[5]<<16), (unsigned)v[6]|((unsigned)v[7]<<16));
        }
        return;
    }

    // ---- transpose branch: sv rows [m0, m0+64) x t cols [t0, t0+64) ----
    const float* o_sv = region(outv, 4);
    const int bx = blk & 31;
    const int m0 = (blk >> 5) * 64;            // 0,64,128,192,256
    const int t0 = bx*64;
    const int c = tid & 7, r0 = tid >> 3;

    #pragma unroll
    for (int h = 0; h < 2; h++){
        const int r = r0 + 32*h;
        const int m = m0 + r;
        float v[8] = {0,0,0,0,0,0,0,0};
        if (m < Nn) ld8(o_sv, (size_t)m*Tt + t0 + c*8, v);
        unsigned short* d = &tile[r][c*8];
        #pragma unroll
        for (int j = 0; j < 8; j++) d[j] = f2bu(v[j]);
    }
    __syncthreads();

    const int kb0 = m0 >> 5;
    #pragma unroll
    for (int i = 0; i < 2; i++){
        const int fid = tid + 256*i;           // 0..511
        const int nt_loc = fid >> 7;           // 0..3
        const int kb_loc = (fid >> 6) & 1;     // 0..1
        const int l  = fid & 63;
        const int ln = l & 15, quad = l >> 4;
        const int nt = bx*4 + nt_loc;
        unsigned short sv[8], av[8];
        #pragma unroll
        for (int j = 0; j < 8; j++){
            unsigned short u = tile[kb_loc*32 + quad*8 + j][nt_loc*16 + ln];
            sv[j] = u;
            av[j] = (u & 0x8000u) ? (unsigned short)0 : u;   // relu on bf16 bits
        }
        *(uint4*)(xt_sw + ((size_t)(nt*NKB + kb0 + kb_loc)*64 + l)*8) =
            make_uint4((unsigned)av[0]|((unsigned)av[1]<<16), (unsigned)av[2]|((unsigned)av[3]<<16),
                       (unsigned)av[4]|((unsigned)av[5]<<16), (unsigned)av[6]|((unsigned)av[7]<<16));
        *(uint4*)(xt_sw + ((size_t)(nt*NKB + 10 + kb0 + kb_loc)*64 + l)*8) =
            make_uint4((unsigned)sv[0]|((unsigned)sv[1]<<16), (unsigned)sv[2]|((unsigned)sv[3]<<16),
                       (unsigned)sv[4]|((unsigned)sv[5]<<16), (unsigned)sv[6]|((unsigned)sv[7]<<16));
    }
}

// ============ Kernel G: MFMA GEMM on swizzled frags + f32 epilogue ============
// grid (32, NMT): 4 waves/block, wave w -> nt = bx*4+w, mt = by.
__global__ __launch_bounds__(256) void kG(
    const unsigned short* __restrict__ wc_sw, const unsigned short* __restrict__ xt_sw,
    const float* __restrict__ bias, const float* __restrict__ tau,
    void* outv)
{
    __shared__ float C[16][68];
    const int tid = threadIdx.x;
    const int wave = tid >> 6, lane = tid & 63;
    const int ln = lane & 15, quad = lane >> 4;
    const int bx = blockIdx.x, by = blockIdx.y;
    const int nt = bx*4 + wave;

    const unsigned short* Ap = wc_sw + (size_t)by*NKB*512 + lane*8;
    const unsigned short* Bp = xt_sw + (size_t)nt*NKB*512 + lane*8;

    f32x4 acc = {0.f,0.f,0.f,0.f};
    #pragma unroll
    for (int kb = 0; kb < NKB; kb++){
        short8 a = *(const short8*)(Ap + kb*512);
        short8 b = *(const short8*)(Bp + kb*512);
        acc = __builtin_amdgcn_mfma_f32_16x16x32_bf16(a, b, acc, 0, 0, 0);
    }

    #pragma unroll
    for (int r = 0; r < 4; r++) C[quad*4 + r][wave*16 + ln] = acc[r];
    __syncthreads();

    if (tid < 128){
        const int m_loc = tid >> 3, strip = tid & 7;
        const int m = by*16 + m_loc;
        if (m < Nn){
            const float* o_sv = region(outv, 4);
            const float* o_si = region(outv, 8);
            float* o_mnv = region(outv, 0);
            float* o_rec = region(outv, 7);
            const int t = bx*64 + strip*8;
            const size_t idx = (size_t)m*Tt + t;
            float si[8], sv[8], rec[8], mnv[8];
            ld8(o_si, idx, si);
            ld8(o_sv, idx, sv);
            const float it = DTc / tau[m];
            const float bi = bias[m];
            #pragma unroll
            for (int j = 0; j < 8; j++){
                float rc = C[m_loc][strip*8 + j] + si[j];
                rec[j] = rc;
                mnv[j] = sv[j] + it*(-sv[j] + rc + bi);
            }
            st8(o_rec, idx, rec);
            st8(o_mnv, idx, mnv);
        }
    }
}

// ============ scalar f32 fallback GEMM (R2/R3-proven; only if ws too small) ============
__global__ __launch_bounds__(256) void kBs(
    const float* __restrict__ Wch, const float* __restrict__ Wel,
    const float* __restrict__ bias, const float* __restrict__ tau,
    void* outv)
{
    const int tx = threadIdx.x & 63, ty = threadIdx.x >> 6;
    const int t  = blockIdx.x*64 + tx;
    const int n0 = blockIdx.y*32;

    const float* o_sv = region(outv, 4);
    const float* o_si = region(outv, 8);
    float* o_mnv = region(outv, 0);
    float* o_rec = region(outv, 7);

    int nn[8]; size_t pb[8]; float acc[8];
    #pragma unroll
    for (int r = 0; r < 8; r++){
        int v = n0 + ty + 4*r;
        nn[r] = v;
        pb[r] = (size_t)((v < Nn) ? v : 0) * 151;
        acc[r] = 0.f;
    }
    for (int mh = 0; mh < 151; mh++){
        const int m = mh*2;
        float s0 = o_sv[(size_t)m*Tt + t];
        float s1 = o_sv[(size_t)(m+1)*Tt + t];
        float a0 = fmaxf(s0,0.f), a1 = fmaxf(s1,0.f);
        #pragma unroll
        for (int r = 0; r < 8; r++){
            float2 wc = ((const float2*)Wch)[pb[r] + mh];
            float2 we = ((const float2*)Wel)[pb[r] + mh];
            acc[r] = fmaf(wc.x, a0, acc[r]);
            acc[r] = fmaf(wc.y, a1, acc[r]);
            acc[r] = fmaf(we.x, s0, acc[r]);
            acc[r] = fmaf(we.y, s1, acc[r]);
        }
    }
    #pragma unroll
    for (int r = 0; r < 8; r++){
        if (nn[r] < Nn){
            const size_t idx = (size_t)nn[r]*Tt + t;
            float rec = acc[r] + o_si[idx];
            o_rec[idx] = rec;
            float sv = o_sv[idx];
            o_mnv[idx] = sv + (DTc/tau[nn[r]])*(-sv + rec + bias[nn[r]]);
        }
    }
}

extern "C" void kernel_launch(void* const* d_in, const int* in_sizes, int n_in,
                              void* d_out, int out_size, void* d_ws, size_t ws_size,
                              hipStream_t stream) {
    const float* fr   = (const float*)d_in[0];
    const float* fft  = (const float*)d_in[1];
    const float* odor = (const float*)d_in[2];
    const float* eps  = (const float*)d_in[3];
    const float* Wenc = (const float*)d_in[4];
    const float* benc = (const float*)d_in[5];
    const float* mask = (const float*)d_in[6];
    const float* Wmf  = (const float*)d_in[7];
    const float* Wms  = (const float*)d_in[8];
    const float* bmu  = (const float*)d_in[9];
    const float* Wlf  = (const float*)d_in[10];
    const float* Wls  = (const float*)d_in[11];
    const float* blv  = (const float*)d_in[12];
    const float* Wch  = (const float*)d_in[13];
    const float* Wel  = (const float*)d_in[14];
    const float* bias = (const float*)d_in[15];
    const float* tau  = (const float*)d_in[16];
    const float* waff = (const float*)d_in[17];
    const float* baff = (const float*)d_in[18];
    const float* scal = (const float*)d_in[19];
    const float* shft = (const float*)d_in[20];
    const float* ctau = (const float*)d_in[21];

    kA<<<Nn, 256, 0, stream>>>(fr, odor, eps, Wenc, benc, mask, Wmf, Wms, bmu,
                               Wlf, Wls, blv, waff, baff, fft, scal, shft, ctau, d_out);

    const size_t XT_ELEMS = (size_t)NNT*NKB*64*8;                    // 1,310,720 u16
    const size_t WS_NEED  = (XT_ELEMS + (size_t)NMT*NKB*64*8) * 2;   // 3,010,560 B (proven fit)
    if (ws_size >= WS_NEED){
        unsigned short* xt_sw = (unsigned short*)d_ws;
        unsigned short* wc_sw = xt_sw + XT_ELEMS;
        kTP<<<160 + NMT, 256, 0, stream>>>(Wch, Wel, d_out, xt_sw, wc_sw);
        kG<<<dim3(32, NMT), 256, 0, stream>>>(wc_sw, xt_sw, bias, tau, d_out);
    } else {
        kBs<<<dim3(32, 10), 256, 0, stream>>>(Wch, Wel, bias, tau, d_out);
    }
}